// Round 11
// baseline (127.878 us; speedup 1.0000x reference)
//
#include <hip/hip_runtime.h>

#define IN_F 1024
#define OUT_F 1024
#define NNZ 16384

typedef _Float16 f16;
typedef _Float16 f16x4 __attribute__((ext_vector_type(4)));
typedef _Float16 f16x8 __attribute__((ext_vector_type(8)));
typedef float f32x4 __attribute__((ext_vector_type(4)));
typedef unsigned short ushort8 __attribute__((ext_vector_type(8)));

#define AS1 __attribute__((address_space(1)))
#define AS3 __attribute__((address_space(3)))

// ---------------------------------------------------------------------------
// Workspace: S = staged W_eff (f16, 2 MiB) @0; mode flag @2MiB; Xs @2MiB+4096.
// Staged layout (quarters, both S and Xs): quarter qidx = g2*16 + kt
// (g2 = 64-row group, kt = 64-K tile) = [64 rows][64 k] = 512 slots x 16B;
// slot u = r*8 + bb holds M[g2*64+r][kt*64 + ((bb^(r&7))<<3) .. +8].
// Proven 128B-row-stride + 8-way-XOR layout (0 bank conflicts, r8/r10).
//
// SYNC INVARIANT (r9): DMA-staged LDS is written by ALL waves; vmcnt drains
// only the issuing wave's loads -> every cross-wave read of a staged buffer
// must be preceded by VMW(n) -> s_barrier.
// ---------------------------------------------------------------------------

__global__ void detect_mode(const unsigned short* __restrict__ w, int* __restrict__ mode) {
  __shared__ float smax[256];
  __shared__ int semax[256];
  int t = threadIdx.x;
  const float* wf = (const float*)w;
  float m32 = fabsf(wf[t]);
  m32 = fmaxf(m32, fabsf(wf[t + 256]));
  int e8 = 0;
#pragma unroll
  for (int j = 0; j < 8; ++j) {
    unsigned short u = w[t * 8 + j];
    int e = (u >> 7) & 0xFF;
    e8 = e > e8 ? e : e8;
  }
  smax[t] = m32; semax[t] = e8;
  __syncthreads();
  for (int s = 128; s > 0; s >>= 1) {
    if (t < s) {
      smax[t] = fmaxf(smax[t], smax[t + s]);
      semax[t] = semax[t] > semax[t + s] ? semax[t] : semax[t + s];
    }
    __syncthreads();
  }
  if (t == 0) {
    int m;
    if (!(smax[0] > 1e-6f)) m = 2;        // native f16
    else if (semax[0] >= 140) m = 0;      // f32 (upcast from fp16)
    else m = 1;                           // bf16
    *mode = m;
  }
}

__device__ __forceinline__ float load_w(const void* base, size_t i, int mode) {
  if (mode == 0) return ((const float*)base)[i];
  if (mode == 1) {
    unsigned int u = (unsigned int)((const unsigned short*)base)[i] << 16;
    return __uint_as_float(u);
  }
  return (float)((const f16*)base)[i];
}

__global__ void prep_base(const void* __restrict__ base, f16* __restrict__ S,
                          const int* __restrict__ modep) {
  int mode = *modep;
  int id = blockIdx.x * 256 + threadIdx.x;   // slot id, 131072 total
  int u = id & 511;
  int qidx = id >> 9;                        // 256 quarters
  int kt = qidx & 15;
  int g2 = qidx >> 4;
  int r = u >> 3, bb = u & 7;
  int n = g2 * 64 + r;
  int k = kt * 64 + ((bb ^ (r & 7)) << 3);
  size_t off = (size_t)n * IN_F + k;
  f16x8 h;
  if (mode == 0) {
    const float* b = (const float*)base + off;
    float4 v0 = *reinterpret_cast<const float4*>(b);
    float4 v1 = *reinterpret_cast<const float4*>(b + 4);
    h = (f16x8){(f16)v0.x, (f16)v0.y, (f16)v0.z, (f16)v0.w,
                (f16)v1.x, (f16)v1.y, (f16)v1.z, (f16)v1.w};
  } else if (mode == 1) {
    ushort8 uv = *reinterpret_cast<const ushort8*>((const unsigned short*)base + off);
#pragma unroll
    for (int j = 0; j < 8; ++j)
      h[j] = (f16)__uint_as_float((unsigned int)uv[j] << 16);
  } else {
    h = *reinterpret_cast<const f16x8*>((const f16*)base + off);
  }
  *reinterpret_cast<f16x8*>(S + (size_t)id * 8) = h;
}

__global__ void prep_scatter(const void* __restrict__ base,
                             const void* __restrict__ vals,
                             const int* __restrict__ idx,
                             const float* __restrict__ alpha,
                             f16* __restrict__ S,
                             const int* __restrict__ modep) {
  int mode = *modep;
  int i = blockIdx.x * 256 + threadIdx.x;
  if (i >= NNZ) return;
  int id = idx[i];
  int n = id >> 10, k = id & 1023;
  float v = load_w(base, id, mode) + alpha[0] * load_w(vals, i, mode);
  int g2 = n >> 6, r = n & 63;
  int kt = k >> 6, kk = k & 63;
  int b = kk >> 3, e = kk & 7;
  int bb = b ^ (r & 7);
  size_t pos = (((size_t)(g2 * 16 + kt)) * 512 + (size_t)(r * 8 + bb)) * 8 + (size_t)e;
  S[pos] = (f16)v;
}

// conv_x: thread unit = one staged 16B slot -> stores fully contiguous
// (1 KiB per wave); loads are 32B pieces permuted within a 256B row segment.
__global__ void __launch_bounds__(256) conv_x(const float* __restrict__ X,
                                              f16* __restrict__ Xs, int total) {
  int stride = gridDim.x * 256;
  for (int id = blockIdx.x * 256 + threadIdx.x; id < total; id += stride) {
    int u = id & 511;
    int qidx = id >> 9;
    int kt = qidx & 15;
    int g2 = qidx >> 4;
    int r = u >> 3, bb = u & 7;
    int b = bb ^ (r & 7);
    size_t row = (size_t)g2 * 64 + r;
    const float* p = X + row * IN_F + kt * 64 + b * 8;
    float4 v0 = *reinterpret_cast<const float4*>(p);
    float4 v1 = *reinterpret_cast<const float4*>(p + 4);
    f16x8 h = {(f16)v0.x, (f16)v0.y, (f16)v0.z, (f16)v0.w,
               (f16)v1.x, (f16)v1.y, (f16)v1.z, (f16)v1.w};
    *reinterpret_cast<f16x8*>(Xs + (size_t)id * 8) = h;   // contiguous
  }
}

#define SB0 __builtin_amdgcn_sched_barrier(0)
#define VMW(N) asm volatile("s_waitcnt vmcnt(" #N ")" ::: "memory")

// ---------------------------------------------------------------------------
// gemm6: subtile-pipelined 256x256, BK=64, 512 thr (8 waves 2Mx4N), wave tile
// 128x64. LDS 128 KiB: sA/sB = [2buf][4 row-quarters][64][64] f16.
// Each K-tile = 4 subphases of 16 MFMA; each subphase's ds_reads (4 or 8 x
// b128) are issued ONE SUBPHASE EARLY into register-double-buffered fragment
// sets (aC/aN, b0/b1) -> LDS service overlaps the MFMA windows; the wait
// before each MFMA cluster is compiler-counted (lgkmcnt(8)-style), never 0.
// Barriers: 2 per tile (mid-tile RAW gate for the DMA'd buffer, end-of-tile
// WAR gate). vmcnt(0) only at the RAW gate (flight = 2 subphases >= latency).
// ---------------------------------------------------------------------------

#define ISSUE_QA(QI, KT1, PB)                                                  \
    __builtin_amdgcn_global_load_lds(                                          \
        (const AS1 void*)(Xs + ((size_t)((mt * 4 + (QI)) * 16 + (KT1))) * 4096 + t * 8), \
        (AS3 void*)(&sA[((PB) * 4 + (QI)) * 4096 + t * 8]), 16, 0, 0)

#define ISSUE_QB(QI, KT1, PB)                                                  \
    __builtin_amdgcn_global_load_lds(                                          \
        (const AS1 void*)(Swz + ((size_t)((nt * 4 + (QI)) * 16 + (KT1))) * 4096 + t * 8), \
        (AS3 void*)(&sB[((PB) * 4 + (QI)) * 4096 + t * 8]), 16, 0, 0)

// 4 A-fragment reads for (quadrant QQ, k-half S_) from buffer P
#define RD_A(DST, QQ, S_, P) do {                                              \
    int qa_ = ((P) * 4 + wm * 2 + (QQ)) * 4096;                                \
    _Pragma("unroll")                                                          \
    for (int mf_ = 0; mf_ < 4; ++mf_) {                                        \
      int r_ = mf_ * 16 + lr;                                                  \
      int blk_ = ((S_) * 4 + lk) ^ (lr & 7);                                   \
      DST[mf_] = *reinterpret_cast<const f16x8*>(&sA[qa_ + r_ * 64 + blk_ * 8]); \
    }                                                                          \
  } while (0)

// 4 B-fragment reads for k-half S_ from buffer P
#define RD_B(DST, S_, P) do {                                                  \
    int qb_ = ((P) * 4 + wn) * 4096;                                           \
    _Pragma("unroll")                                                          \
    for (int nf_ = 0; nf_ < 4; ++nf_) {                                        \
      int r_ = nf_ * 16 + lr;                                                  \
      int blk_ = ((S_) * 4 + lk) ^ (lr & 7);                                   \
      DST[nf_] = *reinterpret_cast<const f16x8*>(&sB[qb_ + r_ * 64 + blk_ * 8]); \
    }                                                                          \
  } while (0)

#define MFMA16(QQ, AARR, BARR) do {                                            \
    __builtin_amdgcn_s_setprio(1);                                             \
    _Pragma("unroll")                                                          \
    for (int mf_ = 0; mf_ < 4; ++mf_)                                          \
      _Pragma("unroll")                                                        \
      for (int nf_ = 0; nf_ < 4; ++nf_)                                        \
        acc[(QQ) * 4 + mf_][nf_] = __builtin_amdgcn_mfma_f32_16x16x32_f16(     \
            AARR[mf_], BARR[nf_], acc[(QQ) * 4 + mf_][nf_], 0, 0, 0);          \
    __builtin_amdgcn_s_setprio(0);                                             \
  } while (0)

// Pre-tile invariant: aC = A(Q0,S0), b0 = B(S0) of tile KT (buffer P) loaded.
#define TILE6(P, KT, PREF) do {                                                \
    /* ---- phase A ---- */                                                    \
    if (PREF) { ISSUE_QA(0, (KT) + 1, (P) ^ 1); ISSUE_QA(1, (KT) + 1, (P) ^ 1);\
                ISSUE_QA(2, (KT) + 1, (P) ^ 1); ISSUE_QA(3, (KT) + 1, (P) ^ 1);\
                ISSUE_QB(0, (KT) + 1, (P) ^ 1); ISSUE_QB(1, (KT) + 1, (P) ^ 1);\
                ISSUE_QB(2, (KT) + 1, (P) ^ 1); ISSUE_QB(3, (KT) + 1, (P) ^ 1); } \
    SB0;                                                                       \
    RD_A(aN, 1, 0, P);            /* f1 prefetch: A(Q1,S0) */                  \
    SB0;                                                                       \
    MFMA16(0, aC, b0);            /* f1 compute: (Q0,S0)   */                  \
    SB0;                                                                       \
    RD_A(aC, 0, 1, P); RD_B(b1, 1, P);   /* f2 prefetch: A(Q0,S1), B(S1) */    \
    SB0;                                                                       \
    MFMA16(1, aN, b0);            /* f2 compute: (Q1,S0)   */                  \
    SB0;                                                                       \
    /* ---- phase B ---- */                                                    \
    VMW(0);                                                                    \
    SB0;                                                                       \
    __builtin_amdgcn_s_barrier();  /* RAW gate: buf P^1 resident */            \
    SB0;                                                                       \
    RD_A(aN, 1, 1, P);            /* f3 prefetch: A(Q1,S1) */                  \
    SB0;                                                                       \
    MFMA16(0, aC, b1);            /* f3 compute: (Q0,S1)   */                  \
    SB0;                                                                       \
    if (PREF) { RD_A(aC, 0, 0, (P) ^ 1); RD_B(b0, 0, (P) ^ 1); }               \
    SB0;                          /* f4 prefetch: next tile (Q0,S0),B(S0) */   \
    MFMA16(1, aN, b1);            /* f4 compute: (Q1,S1)   */                  \
    SB0;                                                                       \
    __builtin_amdgcn_s_barrier();  /* WAR gate: reads of P complete */         \
    SB0;                                                                       \
  } while (0)

__global__ void __launch_bounds__(512, 2) gemm6(const f16* __restrict__ Xs,
                                                const f16* __restrict__ Swz,
                                                float* __restrict__ C) {
  extern __shared__ f16 lds[];
  f16* sA = lds;            // [2buf][4 quarters][4096]
  f16* sB = lds + 32768;

  int bidx = blockIdx.x;
  int q = gridDim.x >> 3;
  int wg = (bidx & 7) * q + (bidx >> 3);
  int mt = wg >> 2, nt = wg & 3;

  int t = threadIdx.x;
  int lane = t & 63;
  int w = t >> 6;
  int wm = w >> 2;           // M half (128 rows) -> A quarters 2wm, 2wm+1
  int wn = w & 3;            // N quarter (64 cols) == B row-quarter
  int lr = lane & 15;
  int lk = lane >> 4;

  f16x8 aC[4], aN[4], b0[4], b1[4];
  f32x4 acc[8][4];
#pragma unroll
  for (int i = 0; i < 8; ++i)
#pragma unroll
    for (int j = 0; j < 4; ++j)
      acc[i][j] = (f32x4){0.f, 0.f, 0.f, 0.f};

  // prologue: DMA tile 0 -> buf0; drain+barrier (r9 invariant); preload f1 frags
  ISSUE_QA(0, 0, 0); ISSUE_QA(1, 0, 0); ISSUE_QA(2, 0, 0); ISSUE_QA(3, 0, 0);
  ISSUE_QB(0, 0, 0); ISSUE_QB(1, 0, 0); ISSUE_QB(2, 0, 0); ISSUE_QB(3, 0, 0);
  VMW(0);
  __builtin_amdgcn_s_barrier();
  SB0;
  RD_A(aC, 0, 0, 0); RD_B(b0, 0, 0);
  SB0;

  for (int kt2 = 0; kt2 < 14; kt2 += 2) {
    TILE6(0, kt2, true);
    TILE6(1, kt2 + 1, true);
  }
  TILE6(0, 14, true);
  TILE6(1, 15, false);

  float* Cw = C + (size_t)(mt * 256 + wm * 128 + lk * 4) * OUT_F + nt * 256 + wn * 64 + lr;
#pragma unroll
  for (int m = 0; m < 8; ++m) {
    int rowo = (m >> 2) * 64 + (m & 3) * 16;
#pragma unroll
    for (int nf = 0; nf < 4; ++nf)
#pragma unroll
      for (int g = 0; g < 4; ++g)
        Cw[(size_t)(rowo + g) * OUT_F + nf * 16] = acc[m][nf][g];
  }
}

extern "C" void kernel_launch(void* const* d_in, const int* in_sizes, int n_in,
                              void* d_out, int out_size, void* d_ws, size_t ws_size,
                              hipStream_t stream) {
  const float* X = (const float*)d_in[0];
  const void* base = d_in[1];
  const void* vals = d_in[2];
  const int* idx = (const int*)d_in[3];
  const float* alpha = (const float*)d_in[4];
  float* out = (float*)d_out;
  f16* S = (f16*)d_ws;
  int* modep = (int*)((char*)d_ws + 2 * 1024 * 1024);
  f16* Xs = (f16*)((char*)d_ws + 2 * 1024 * 1024 + 4096);

  int M = in_sizes[0] / IN_F;              // 32768
  int total = (M * IN_F) / 8;              // staged 16B slots

  (void)hipFuncSetAttribute(reinterpret_cast<const void*>(&gemm6),
                            hipFuncAttributeMaxDynamicSharedMemorySize, 131072);

  detect_mode<<<dim3(1), dim3(256), 0, stream>>>((const unsigned short*)base, modep);
  prep_base<<<dim3(512), dim3(256), 0, stream>>>(base, S, modep);
  prep_scatter<<<dim3((NNZ + 255) / 256), dim3(256), 0, stream>>>(base, vals, idx, alpha, S, modep);
  conv_x<<<dim3(2048), dim3(256), 0, stream>>>(X, Xs, total);
  gemm6<<<dim3((M / 256) * 4), dim3(512), 131072, stream>>>(Xs, S, out);
}